// Round 6
// baseline (205.747 us; speedup 1.0000x reference)
//
#include <hip/hip_runtime.h>
#include <hip/hip_bf16.h>
#include <math.h>
#include <stdint.h>

#define BB 32
#define CC 256
#define SS 1024
// TEMP = 0.1 -> multiply by 10

typedef __attribute__((ext_vector_type(8))) short short8v;
typedef __attribute__((ext_vector_type(4))) float f32x4;

#define ASYNC16(g, l)                                                        \
  __builtin_amdgcn_global_load_lds(                                          \
      (const __attribute__((address_space(1))) void*)(g),                    \
      (__attribute__((address_space(3))) void*)(l), 16, 0, 0)

__device__ __forceinline__ unsigned short bf16_rne(float f) {
  unsigned int u = __float_as_uint(f);
  unsigned int r = (u + 0x7fffu + ((u >> 16) & 1u)) >> 16;
  return (unsigned short)r;
}

// Threefry-2x32-20 round
__device__ __forceinline__ void tf_round(uint32_t& x0, uint32_t& x1, int r) {
  x0 += x1;
  x1 = (x1 << r) | (x1 >> (32 - r));
  x1 ^= x0;
}

// Generates u[t] and u[t+512] for JAX key(42), matching jax.random.uniform(key,(32,32))
__device__ __forceinline__ void tf_gen(int t, float* u) {
  uint32_t x0 = (uint32_t)t;
  uint32_t x1 = (uint32_t)(t + 512);
  const uint32_t ks0 = 0u, ks1 = 42u, ks2 = 0x1BD11BDAu ^ 0u ^ 42u;
  x0 += ks0; x1 += ks1;
  tf_round(x0, x1, 13); tf_round(x0, x1, 15); tf_round(x0, x1, 26); tf_round(x0, x1, 6);
  x0 += ks1; x1 += ks2 + 1u;
  tf_round(x0, x1, 17); tf_round(x0, x1, 29); tf_round(x0, x1, 16); tf_round(x0, x1, 24);
  x0 += ks2; x1 += ks0 + 2u;
  tf_round(x0, x1, 13); tf_round(x0, x1, 15); tf_round(x0, x1, 26); tf_round(x0, x1, 6);
  x0 += ks0; x1 += ks1 + 3u;
  tf_round(x0, x1, 17); tf_round(x0, x1, 29); tf_round(x0, x1, 16); tf_round(x0, x1, 24);
  x0 += ks1; x1 += ks2 + 4u;
  tf_round(x0, x1, 13); tf_round(x0, x1, 15); tf_round(x0, x1, 26); tf_round(x0, x1, 6);
  x0 += ks2; x1 += ks0 + 5u;
  u[t]       = __uint_as_float((x0 >> 9) | 0x3f800000u) - 1.0f;
  u[t + 512] = __uint_as_float((x1 >> 9) | 0x3f800000u) - 1.0f;
}

// ---------------------------------------------------------------------------
// transnorm v4b: [C][S] f32 -> [S][C] bf16 + per-s inv L2 norm over C.
// NOTE (r1-r4): three structurally different variants all measure 43-47us
// @ ~2.3TB/s — structural rate for 4KB-stride f32 gathers; not tuned further.
// ---------------------------------------------------------------------------
__global__ __launch_bounds__(256, 4) void transnorm_kernel(
    const float* __restrict__ qb, const float* __restrict__ kb,
    const float* __restrict__ kg, unsigned short* __restrict__ qt,
    unsigned short* __restrict__ kt, unsigned short* __restrict__ kgt,
    float* __restrict__ invqb, float* __restrict__ invkb,
    float* __restrict__ invkg, const int* __restrict__ labels,
    int* __restrict__ negidx, unsigned long long* __restrict__ best,
    float* __restrict__ out) {
  const int bid = blockIdx.x;
  const int tid = threadIdx.x;

  __shared__ unsigned int tile[64 * 128];  // packed bf16 pairs, XOR-swizzled
  __shared__ float part[16][65];

  if (bid >= 1536) {
    if (bid == 1536) {
      // --- negidx: threefry u[32][32] + per-b argmax over different-label ---
      float* u = (float*)&tile[0];  // reuse LDS (needs 4 KB)
      tf_gen(tid, u);
      tf_gen(tid + 256, u);
      if (tid == 0) *out = 0.f;
      __syncthreads();
      if (tid < BB) {
        int lb = labels[tid];
        float bestv = -1.0f;
        int bj = 0;
        for (int j = 0; j < BB; ++j) {
          float v = (labels[j] != lb) ? u[tid * BB + j] : -1.0f;
          if (v > bestv) { bestv = v; bj = j; }
        }
        negidx[tid] = bj;
      }
    } else {
      // --- zero best: 4 blocks x 8192 u64 ---
      unsigned long long* bp = best + (size_t)(bid - 1537) * 8192 + tid;
#pragma unroll
      for (int i = 0; i < 32; ++i) bp[(size_t)i * 256] = 0ull;
    }
    return;
  }

  const int which = bid >> 9;       // 0:qb 1:kb 2:kg
  const int sub = bid & 511;
  const int b = sub >> 4;           // 0..31
  const int s0 = (sub & 15) * 64;   // 0..960

  const float* src = (which == 0) ? qb : (which == 1) ? kb : kg;
  unsigned short* dst = (which == 0) ? qt : (which == 1) ? kt : kgt;
  float* inv = (which == 0) ? invqb : (which == 1) ? invkb : invkg;

  const int sg = tid & 15;   // s-group: rows 4sg..4sg+3
  const int cq = tid >> 4;   // 0..15: cpair = cq + 16k

  const float* sp = src + (size_t)b * CC * SS + s0 + sg * 4;
  float ssq[4] = {0.f, 0.f, 0.f, 0.f};

#pragma unroll
  for (int half = 0; half < 2; ++half) {
    float4 xa[4], xb[4];
#pragma unroll
    for (int kk = 0; kk < 4; ++kk) {
      int cp = cq + 16 * (half * 4 + kk);
      int c = cp * 2;
      xa[kk] = *(const float4*)(sp + ((size_t)c << 10));
      xb[kk] = *(const float4*)(sp + ((size_t)(c + 1) << 10));
    }
#pragma unroll
    for (int kk = 0; kk < 4; ++kk) {
      int cp = cq + 16 * (half * 4 + kk);
      float a[4] = {xa[kk].x, xa[kk].y, xa[kk].z, xa[kk].w};
      float bb[4] = {xb[kk].x, xb[kk].y, xb[kk].z, xb[kk].w};
#pragma unroll
      for (int e = 0; e < 4; ++e) {
        ssq[e] = fmaf(a[e], a[e], ssq[e]);
        ssq[e] = fmaf(bb[e], bb[e], ssq[e]);
        int r = sg * 4 + e;
        int colp = cp ^ (sg << 2);  // swz = (r>>2)<<2 = sg<<2
        tile[r * 128 + colp] =
            (unsigned)bf16_rne(a[e]) | ((unsigned)bf16_rne(bb[e]) << 16);
      }
    }
  }
#pragma unroll
  for (int e = 0; e < 4; ++e) part[cq][sg * 4 + e] = ssq[e];
  __syncthreads();

  // store phase: 8 passes; r = p*8 + (tid>>5), cw = tid&31 -> uint4 (8 bf16)
  const int h = tid >> 5, cw = tid & 31;
  unsigned short* dp = dst + ((size_t)b * SS + s0) * CC;
#pragma unroll
  for (int p = 0; p < 8; ++p) {
    int r = p * 8 + h;
    int colb = (cw * 4) ^ ((r >> 2) << 2);
    uint4 pk = *(const uint4*)&tile[r * 128 + colb];
    *(uint4*)(dp + (size_t)r * CC + cw * 8) = pk;
  }
  if (tid < 64) {
    float s = 0.f;
#pragma unroll
    for (int k = 0; k < 16; ++k) s += part[k][tid];
    inv[b * SS + s0 + tid] = 1.0f / fmaxf(sqrtf(s), 1e-12f);
  }
}

// ---------------------------------------------------------------------------
// simargmax v5: 2-phase double-buffered pipeline (T3-min recipe).
// r5 counters: 48us, MfmaUtil 13.4%, VALU 25%, HBM 0.4TB/s, 0 conflicts ->
// schedule-bound: old loop was load -> vmcnt(0) drain -> compute, serial.
// v5: stage(ch+1) into the other buffer BEFORE compute(ch); one barrier per
// chunk (4 vs 8); loads get the full compute phase to land (L2 ~200-400cy).
// Four DISTINCT __shared__ arrays so alias analysis won't pin ds_reads
// behind vmcnt(0). LDS 67KB -> 2 blocks/CU (~= current 9.3 waves/CU).
// XCD-contiguous swizzle (r5, T1) kept.
// ---------------------------------------------------------------------------
__device__ __forceinline__ void sim_stage(
    const unsigned short* __restrict__ aG, const unsigned short* __restrict__ bG,
    unsigned short* SA, unsigned short* SB, int ch, int w, int r8, int p) {
#pragma unroll
  for (int v = 0; v < 4; ++v) {
    int r = v * 32 + w * 8 + r8;
    int clog = p ^ (r & 7);
    ASYNC16(aG + (size_t)r * CC + ch * 64 + clog * 8, &SA[(v * 32 + w * 8) * 64]);
    ASYNC16(bG + (size_t)r * CC + ch * 64 + clog * 8, &SB[(v * 32 + w * 8) * 64]);
  }
}

__device__ __forceinline__ void sim_compute(
    const unsigned short* SA, const unsigned short* SB, f32x4 acc[4][4],
    int wi, int wj, int q4, int m16) {
#pragma unroll
  for (int kk = 0; kk < 2; ++kk) {
    short8v af[4], bf[4];
#pragma unroll
    for (int mt = 0; mt < 4; ++mt) {
      int i = wi + mt * 16 + m16;
      int cp = (kk * 4 + q4) ^ (i & 7);
      af[mt] = *(const short8v*)&SA[i * 64 + cp * 8];
      int j = wj + mt * 16 + m16;
      int cq = (kk * 4 + q4) ^ (j & 7);
      bf[mt] = *(const short8v*)&SB[j * 64 + cq * 8];
    }
#pragma unroll
    for (int mt = 0; mt < 4; ++mt)
#pragma unroll
      for (int nt = 0; nt < 4; ++nt)
        acc[mt][nt] = __builtin_amdgcn_mfma_f32_16x16x32_bf16(
            af[mt], bf[nt], acc[mt][nt], 0, 0, 0);
  }
}

__global__ __launch_bounds__(256, 2) void simargmax_mfma(
    const unsigned short* __restrict__ qt, const unsigned short* __restrict__ kt,
    const float* __restrict__ invk, unsigned long long* __restrict__ best) {
  const int bid0 = blockIdx.x;
  const int W = (bid0 & 7) * 256 + (bid0 >> 3);  // XCD-contiguous, bijective
  const int b = W >> 6, it = (W >> 3) & 7, jt = W & 7;
  const int t = threadIdx.x, w = t >> 6, l = t & 63;

  __shared__ unsigned short sa0[128 * 64];
  __shared__ unsigned short sa1[128 * 64];
  __shared__ unsigned short sb0[128 * 64];
  __shared__ unsigned short sb1[128 * 64];
  __shared__ unsigned long long cand2[128][2];
  __shared__ float sinvk[128];

  if (t < 128) sinvk[t] = invk[b * SS + jt * 128 + t];

  const unsigned short* aG = qt + ((size_t)b * SS + it * 128) * CC;
  const unsigned short* bG = kt + ((size_t)b * SS + jt * 128) * CC;

  f32x4 acc[4][4];
#pragma unroll
  for (int mt = 0; mt < 4; ++mt)
#pragma unroll
    for (int nt = 0; nt < 4; ++nt) acc[mt][nt] = (f32x4){0.f, 0.f, 0.f, 0.f};

  const int r8 = l >> 3, p = l & 7;
  const int q4 = l >> 4, m16 = l & 15;
  const int wi = (w >> 1) * 64, wj = (w & 1) * 64;

  // ---- 2-phase pipeline over 4 K-chunks ----
  sim_stage(aG, bG, sa0, sb0, 0, w, r8, p);
  __syncthreads();                       // drain ch0 loads
  sim_stage(aG, bG, sa1, sb1, 1, w, r8, p);   // async: fly during compute ch0
  sim_compute(sa0, sb0, acc, wi, wj, q4, m16);
  __syncthreads();                       // drain ch1; all done reading buf0
  sim_stage(aG, bG, sa0, sb0, 2, w, r8, p);
  sim_compute(sa1, sb1, acc, wi, wj, q4, m16);
  __syncthreads();
  sim_stage(aG, bG, sa1, sb1, 3, w, r8, p);
  sim_compute(sa0, sb0, acc, wi, wj, q4, m16);
  __syncthreads();
  sim_compute(sa1, sb1, acc, wi, wj, q4, m16);

  // ---- in-register argmax ----
  // acc[mt][nt][e]: row = wi + mt*16 + q4*4 + e ; local col = wj + nt*16 + m16
  float siv[4];
#pragma unroll
  for (int nt = 0; nt < 4; ++nt) siv[nt] = sinvk[wj + nt * 16 + m16];

  unsigned long long bp[4][4];
#pragma unroll
  for (int mt = 0; mt < 4; ++mt) {
#pragma unroll
    for (int e = 0; e < 4; ++e) {
      unsigned long long mx = 0ull;
#pragma unroll
      for (int nt = 0; nt < 4; ++nt) {
        float v = acc[mt][nt][e] * siv[nt];
        unsigned int u = __float_as_uint(v);
        u = (u & 0x80000000u) ? ~u : (u | 0x80000000u);
        int col = jt * 128 + wj + nt * 16 + m16;
        unsigned long long pk =
            ((unsigned long long)u << 32) | (unsigned)(1023 - col);
        mx = (pk > mx) ? pk : mx;
      }
      bp[mt][e] = mx;
    }
  }
  // butterfly over the 16 column-lanes (m16); rows constant under l^d, d<16
#pragma unroll
  for (int d = 1; d < 16; d <<= 1) {
#pragma unroll
    for (int mt = 0; mt < 4; ++mt)
#pragma unroll
      for (int e = 0; e < 4; ++e) {
        unsigned long long o = __shfl_xor(bp[mt][e], d, 64);
        if (o > bp[mt][e]) bp[mt][e] = o;
      }
  }
  if (m16 == 0) {
#pragma unroll
    for (int mt = 0; mt < 4; ++mt)
#pragma unroll
      for (int e = 0; e < 4; ++e)
        cand2[wi + mt * 16 + q4 * 4 + e][w & 1] = bp[mt][e];
  }
  __syncthreads();
  if (t < 128) {
    unsigned long long m0 = cand2[t][0], m1 = cand2[t][1];
    atomicMax(&best[b * SS + it * 128 + t], m0 > m1 ? m0 : m1);
  }
}

// ---------------------------------------------------------------------------
// negidx standalone (fallback path only)
// ---------------------------------------------------------------------------
__global__ void negidx_kernel(const int* __restrict__ labels, int* __restrict__ negidx) {
  __shared__ float u[1024];
  int t = threadIdx.x;
  tf_gen(t, u);
  __syncthreads();
  if (t < BB) {
    int lb = labels[t];
    float bestv = -1.0f;
    int bj = 0;
    for (int j = 0; j < BB; ++j) {
      float v = (labels[j] != lb) ? u[t * BB + j] : -1.0f;
      if (v > bestv) { bestv = v; bj = j; }
    }
    negidx[t] = bj;
  }
}

// ---------------------------------------------------------------------------
// loss v2 (round-1 measured-best shape): 8 threads per (b,s); 1024 blocks.
// qg norms fused; k rows read as contiguous bf16 from kgt.
// ---------------------------------------------------------------------------
__global__ __launch_bounds__(256) void loss_fused_kernel(
    const float* __restrict__ qg, const unsigned short* __restrict__ kgt,
    const float* __restrict__ invkg, const unsigned long long* __restrict__ best,
    const int* __restrict__ negidx, float* __restrict__ out) {
  const int tid = threadIdx.x;
  const int s_l = tid & 31, g = tid >> 5;
  const int P0 = blockIdx.x * 32;
  const int b = P0 >> 10;
  const int s = (P0 & (SS - 1)) + s_l;
  const int idx = b * SS + s;
  const int js = 1023 - (int)(best[idx] & 0xffffffffu);
  const int nb = negidx[b];

  const float* qcol = qg + ((size_t)b * CC + g * 32) * SS + s;
  const unsigned short* kp = kgt + ((size_t)b * SS + js) * CC + g * 32;
  const unsigned short* kn = kgt + ((size_t)nb * SS + s) * CC + g * 32;

  float dp = 0.f, dn = 0.f, sq = 0.f;
#pragma unroll
  for (int uu = 0; uu < 4; ++uu) {
    uint4 up = *(const uint4*)(kp + uu * 8);
    uint4 un = *(const uint4*)(kn + uu * 8);
    float q[8];
#pragma unroll
    for (int j = 0; j < 8; ++j) {
      q[j] = qcol[(size_t)(uu * 8 + j) << 10];
      sq = fmaf(q[j], q[j], sq);
    }
    float pv[8], nv[8];
    pv[0] = __uint_as_float(up.x << 16); pv[1] = __uint_as_float(up.x & 0xffff0000u);
    pv[2] = __uint_as_float(up.y << 16); pv[3] = __uint_as_float(up.y & 0xffff0000u);
    pv[4] = __uint_as_float(up.z << 16); pv[5] = __uint_as_float(up.z & 0xffff0000u);
    pv[6] = __uint_as_float(up.w << 16); pv[7] = __uint_as_float(up.w & 0xffff0000u);
    nv[0] = __uint_as_float(un.x << 16); nv[1] = __uint_as_float(un.x & 0xffff0000u);
    nv[2] = __uint_as_float(un.y << 16); nv[3] = __uint_as_float(un.y & 0xffff0000u);
    nv[4] = __uint_as_float(un.z << 16); nv[5] = __uint_as_float(un.z & 0xffff0000u);
    nv[6] = __uint_as_float(un.w << 16); nv[7] = __uint_as_float(un.w & 0xffff0000u);
#pragma unroll
    for (int j = 0; j < 8; ++j) {
      dp = fmaf(q[j], pv[j], dp);
      dn = fmaf(q[j], nv[j], dn);
    }
  }

  __shared__ float rdp[8][33], rdn[8][33], rsq[8][33];
  rdp[g][s_l] = dp;
  rdn[g][s_l] = dn;
  rsq[g][s_l] = sq;
  __syncthreads();
  if (tid < 32) {
    float DP = 0.f, DN = 0.f, SQ = 0.f;
#pragma unroll
    for (int k = 0; k < 8; ++k) {
      DP += rdp[k][tid];
      DN += rdn[k][tid];
      SQ += rsq[k][tid];
    }
    int s2 = (P0 & (SS - 1)) + tid;
    int idx2 = b * SS + s2;
    int js2 = 1023 - (int)(best[idx2] & 0xffffffffu);
    float iq = 1.0f / fmaxf(sqrtf(SQ), 1e-12f);
    float pvv = DP * iq * invkg[b * SS + js2] * 10.0f;
    float nvv = DN * iq * invkg[nb * SS + s2] * 10.0f;
    float elem = logf(expf(pvv) + expf(nvv) + 1e-6f) - pvv;
#pragma unroll
    for (int o = 16; o > 0; o >>= 1) elem += __shfl_down(elem, o, 32);
    if (tid == 0) atomicAdd(out, elem * (1.0f / (BB * SS)));
  }
}

// ===========================================================================
// Fallback path (ws too small): round-1 fp32 VALU, known correct.
// ===========================================================================
__global__ __launch_bounds__(256) void norms_kernel(
    const float* __restrict__ qb, const float* __restrict__ kb,
    const float* __restrict__ qg, const float* __restrict__ kg,
    float* __restrict__ inv) {
  int t = blockIdx.x * 256 + threadIdx.x;
  int which = t >> 15;
  int bs = t & (BB * SS - 1);
  const float* src = (which == 0) ? qb : (which == 1) ? kb : (which == 2) ? qg : kg;
  int b = bs >> 10;
  int s = bs & (SS - 1);
  const float* p = src + (size_t)b * CC * SS + s;
  float ss = 0.f;
#pragma unroll 8
  for (int c = 0; c < CC; ++c) {
    float x = p[(size_t)c * SS];
    ss = fmaf(x, x, ss);
  }
  float n = fmaxf(sqrtf(ss), 1e-12f);
  inv[t] = 1.0f / n;
}

#define TI 64
#define TJ 128
#define KC 32

__global__ __launch_bounds__(256) void simargmax_kernel(
    const float* __restrict__ qb, const float* __restrict__ kb,
    const float* __restrict__ invq, const float* __restrict__ invk,
    int* __restrict__ amax) {
  const int b = blockIdx.x >> 4;
  const int i0 = (blockIdx.x & 15) * TI;
  const int t = threadIdx.x;
  const int ti = t >> 4;
  const int tj = t & 15;

  __shared__ float aQ[KC][TI];
  __shared__ float bK[KC][TJ];
  __shared__ float redv[TI][16];
  __shared__ int redj[TI][16];

  const float* qbase = qb + (size_t)b * CC * SS + i0;
  const float* kbase = kb + (size_t)b * CC * SS;
  const float* ivq = invq + b * SS + i0;
  const float* ivk = invk + b * SS;

  float best_v = -3.4e38f;
  int best_j = 0;

  for (int j0 = 0; j0 < SS; j0 += TJ) {
    float acc[4][8];
#pragma unroll
    for (int r = 0; r < 4; ++r)
#pragma unroll
      for (int rr = 0; rr < 8; ++rr) acc[r][rr] = 0.f;

    for (int c0 = 0; c0 < CC; c0 += KC) {
      __syncthreads();
#pragma unroll
      for (int v = 0; v < 2; ++v) {
        int f = t + v * 256;
        int cl = f >> 4;
        int sl = (f & 15) << 2;
        float4 qa = *(const float4*)(qbase + (size_t)(c0 + cl) * SS + sl);
        float4 iv = *(const float4*)(ivq + sl);
        aQ[cl][sl + 0] = qa.x * iv.x;
        aQ[cl][sl + 1] = qa.y * iv.y;
        aQ[cl][sl + 2] = qa.z * iv.z;
        aQ[cl][sl + 3] = qa.w * iv.w;
      }
#pragma unroll
      for (int v = 0; v < 4; ++v) {
        int f = t + v * 256;
        int cl = f >> 5;
        int sl = (f & 31) << 2;
        float4 ka = *(const float4*)(kbase + (size_t)(c0 + cl) * SS + j0 + sl);
        float4 ik = *(const float4*)(ivk + j0 + sl);
        bK[cl][sl + 0] = ka.x * ik.x;
        bK[cl][sl + 1] = ka.y * ik.y;
        bK[cl][sl + 2] = ka.z * ik.z;
        bK[cl][sl + 3] = ka.w * ik.w;
      }
      __syncthreads();
#pragma unroll
      for (int kc = 0; kc < KC; ++kc) {
        float4 a0 = *(const float4*)&aQ[kc][ti * 4];
        float4 b0 = *(const float4*)&bK[kc][tj * 8];
        float4 b1 = *(const float4*)&bK[kc][tj * 8 + 4];
        float av[4] = {a0.x, a0.y, a0.z, a0.w};
        float bv[8] = {b0.x, b0.y, b0.z, b0.w, b1.x, b1.y, b1.z, b1.w};
#pragma unroll
        for (int r = 0; r < 4; ++r)
#pragma unroll
          for (int rr = 0; rr < 8; ++rr)
            acc[r][rr] = fmaf(av[r], bv[rr], acc[r][rr]);
      }
    }
    __syncthreads();
#pragma unroll
    for (int r = 0; r < 4; ++r) {
      float v = acc[r][0];
      int jb = j0 + tj * 8;
#pragma unroll
      for (int rr = 1; rr < 8; ++rr) {
        if (acc[r][rr] > v) { v = acc[r][rr]; jb = j0 + tj * 8 + rr; }
      }
      redv[ti * 4 + r][tj] = v;
      redj[ti * 4 + r][tj] = jb;
    }
    __syncthreads();
    if (t < TI) {
#pragma unroll
      for (int ww = 0; ww < 16; ++ww) {
        float v = redv[t][ww];
        if (v > best_v) { best_v = v; best_j = redj[t][ww]; }
      }
    }
  }
  if (t < TI) amax[b * SS + i0 + t] = best_j;
}

__global__ __launch_bounds__(256) void loss_kernel(
    const float* __restrict__ qg, const float* __restrict__ kg,
    const float* __restrict__ invq, const float* __restrict__ invk,
    const int* __restrict__ amax, const int* __restrict__ negidx,
    float* __restrict__ out) {
  int t = blockIdx.x * 256 + threadIdx.x;
  int b = t >> 10;
  int s = t & (SS - 1);
  int js = amax[t];
  int nb = negidx[b];
  const float* qcol = qg + (size_t)b * CC * SS + s;
  const float* kpcol = kg + (size_t)b * CC * SS + js;
  const float* kncol = kg + (size_t)nb * CC * SS + s;
  float dp = 0.f, dn = 0.f;
#pragma unroll 8
  for (int c = 0; c < CC; ++c) {
    float q = qcol[(size_t)c * SS];
    dp = fmaf(q, kpcol[(size_t)c * SS], dp);
    dn = fmaf(q, kncol[(size_t)c * SS], dn);
  }
  float iq = invq[t];
  float pv = dp * iq * invk[b * SS + js] * 10.0f;
  float nv = dn * iq * invk[nb * SS + s] * 10.0f;
  float elem = logf(expf(pv) + expf(nv) + 1e-6f) - pv;

  __shared__ float red[256];
  red[threadIdx.x] = elem;
  __syncthreads();
  for (int o = 128; o > 0; o >>= 1) {
    if (threadIdx.x < o) red[threadIdx.x] += red[threadIdx.x + o];
    __syncthreads();
  }
  if (threadIdx.x == 0) atomicAdd(out, red[0] * (1.0f / (BB * SS)));
}

// ---------------------------------------------------------------------------
extern "C" void kernel_launch(void* const* d_in, const int* in_sizes, int n_in,
                              void* d_out, int out_size, void* d_ws, size_t ws_size,
                              hipStream_t stream) {
  const float* qb = (const float*)d_in[0];
  const float* kb = (const float*)d_in[1];
  const float* qg = (const float*)d_in[2];
  const float* kg = (const float*)d_in[3];
  const int* labels = (const int*)d_in[4];

  char* ws = (char*)d_ws;
  // fast-path layout (49 MB total):
  float* invqb = (float*)ws;                                   // 128 KB (unused)
  float* invkb = (float*)(ws + 128 * 1024);                    // 128 KB
  float* invkg = (float*)(ws + 256 * 1024);                    // 128 KB
  unsigned long long* best = (unsigned long long*)(ws + 384 * 1024);  // 256 KB
  int* negidx = (int*)(ws + 640 * 1024);                       // small
  unsigned short* qt = (unsigned short*)(ws + (1 << 20));      // 16 MB
  unsigned short* kt = (unsigned short*)(ws + (17 << 20));     // 16 MB
  unsigned short* kgt = (unsigned short*)(ws + (33 << 20));    // 16 MB

  const size_t need = (size_t)49 * 1024 * 1024;
  const bool fast = ws_size >= need;

  if (fast) {
    transnorm_kernel<<<1541, 256, 0, stream>>>(qb, kb, kg, qt, kt, kgt, invqb,
                                               invkb, invkg, labels, negidx,
                                               best, (float*)d_out);
    simargmax_mfma<<<2048, 256, 0, stream>>>(qt, kt, invkb, best);
    loss_fused_kernel<<<1024, 256, 0, stream>>>(qg, kgt, invkg, best, negidx,
                                                (float*)d_out);
  } else {
    hipMemsetAsync(d_out, 0, sizeof(float), stream);
    float* inv = (float*)ws;
    int* amax = (int*)(ws + 512 * 1024);
    int* negidx2 = (int*)(ws + 640 * 1024);
    norms_kernel<<<(4 * BB * SS) / 256, 256, 0, stream>>>(qb, kb, qg, kg, inv);
    simargmax_kernel<<<BB * (SS / TI), 256, 0, stream>>>(
        qb, kb, inv + 0 * BB * SS, inv + 1 * BB * SS, amax);
    negidx_kernel<<<1, 512, 0, stream>>>(labels, negidx2);
    loss_kernel<<<(BB * SS) / 256, 256, 0, stream>>>(
        qg, kg, inv + 2 * BB * SS, inv + 3 * BB * SS, amax, negidx2,
        (float*)d_out);
  }
}

// Round 7
// 200.991 us; speedup vs baseline: 1.0237x; 1.0237x over previous
//
#include <hip/hip_runtime.h>
#include <hip/hip_bf16.h>
#include <math.h>
#include <stdint.h>

#define BB 32
#define CC 256
#define SS 1024
// TEMP = 0.1 -> multiply by 10

typedef __attribute__((ext_vector_type(8))) short short8v;
typedef __attribute__((ext_vector_type(4))) float f32x4;

#define ASYNC16(g, l)                                                        \
  __builtin_amdgcn_global_load_lds(                                          \
      (const __attribute__((address_space(1))) void*)(g),                    \
      (__attribute__((address_space(3))) void*)(l), 16, 0, 0)

__device__ __forceinline__ unsigned short bf16_rne(float f) {
  unsigned int u = __float_as_uint(f);
  unsigned int r = (u + 0x7fffu + ((u >> 16) & 1u)) >> 16;
  return (unsigned short)r;
}

// Threefry-2x32-20 round
__device__ __forceinline__ void tf_round(uint32_t& x0, uint32_t& x1, int r) {
  x0 += x1;
  x1 = (x1 << r) | (x1 >> (32 - r));
  x1 ^= x0;
}

// Generates u[t] and u[t+512] for JAX key(42), matching jax.random.uniform(key,(32,32))
__device__ __forceinline__ void tf_gen(int t, float* u) {
  uint32_t x0 = (uint32_t)t;
  uint32_t x1 = (uint32_t)(t + 512);
  const uint32_t ks0 = 0u, ks1 = 42u, ks2 = 0x1BD11BDAu ^ 0u ^ 42u;
  x0 += ks0; x1 += ks1;
  tf_round(x0, x1, 13); tf_round(x0, x1, 15); tf_round(x0, x1, 26); tf_round(x0, x1, 6);
  x0 += ks1; x1 += ks2 + 1u;
  tf_round(x0, x1, 17); tf_round(x0, x1, 29); tf_round(x0, x1, 16); tf_round(x0, x1, 24);
  x0 += ks2; x1 += ks0 + 2u;
  tf_round(x0, x1, 13); tf_round(x0, x1, 15); tf_round(x0, x1, 26); tf_round(x0, x1, 6);
  x0 += ks0; x1 += ks1 + 3u;
  tf_round(x0, x1, 17); tf_round(x0, x1, 29); tf_round(x0, x1, 16); tf_round(x0, x1, 24);
  x0 += ks1; x1 += ks2 + 4u;
  tf_round(x0, x1, 13); tf_round(x0, x1, 15); tf_round(x0, x1, 26); tf_round(x0, x1, 6);
  x0 += ks2; x1 += ks0 + 5u;
  u[t]       = __uint_as_float((x0 >> 9) | 0x3f800000u) - 1.0f;
  u[t + 512] = __uint_as_float((x1 >> 9) | 0x3f800000u) - 1.0f;
}

// ---------------------------------------------------------------------------
// transnorm body: [C][S] f32 -> [S][C] bf16 + per-s inv L2 norm, one
// (b, 64-s strip). LDS: packed bf16-pair u32 [64][128] + part[16][65].
// NOTE (r1-r4): three structurally different variants all measure 43-47us
// @ ~2.3TB/s for 3 tensors — structural rate for 4KB-stride f32 gathers.
// ---------------------------------------------------------------------------
__device__ __forceinline__ void tn_body(const float* __restrict__ src,
                                        unsigned short* __restrict__ dst,
                                        float* __restrict__ inv, int b, int s0,
                                        int tid, unsigned int* tile,
                                        float (*part)[65]) {
  const int sg = tid & 15;   // s-group: rows 4sg..4sg+3
  const int cq = tid >> 4;   // 0..15: cpair = cq + 16k

  const float* sp = src + (size_t)b * CC * SS + s0 + sg * 4;
  float ssq[4] = {0.f, 0.f, 0.f, 0.f};

#pragma unroll
  for (int half = 0; half < 2; ++half) {
    float4 xa[4], xb[4];
#pragma unroll
    for (int kk = 0; kk < 4; ++kk) {
      int cp = cq + 16 * (half * 4 + kk);
      int c = cp * 2;
      xa[kk] = *(const float4*)(sp + ((size_t)c << 10));
      xb[kk] = *(const float4*)(sp + ((size_t)(c + 1) << 10));
    }
#pragma unroll
    for (int kk = 0; kk < 4; ++kk) {
      int cp = cq + 16 * (half * 4 + kk);
      float a[4] = {xa[kk].x, xa[kk].y, xa[kk].z, xa[kk].w};
      float bb[4] = {xb[kk].x, xb[kk].y, xb[kk].z, xb[kk].w};
#pragma unroll
      for (int e = 0; e < 4; ++e) {
        ssq[e] = fmaf(a[e], a[e], ssq[e]);
        ssq[e] = fmaf(bb[e], bb[e], ssq[e]);
        int r = sg * 4 + e;
        int colp = cp ^ (sg << 2);  // swz = (r>>2)<<2 = sg<<2
        tile[r * 128 + colp] =
            (unsigned)bf16_rne(a[e]) | ((unsigned)bf16_rne(bb[e]) << 16);
      }
    }
  }
#pragma unroll
  for (int e = 0; e < 4; ++e) part[cq][sg * 4 + e] = ssq[e];
  __syncthreads();

  // store phase: 8 passes; r = p*8 + (tid>>5), cw = tid&31 -> uint4 (8 bf16)
  const int h = tid >> 5, cw = tid & 31;
  unsigned short* dp = dst + ((size_t)b * SS + s0) * CC;
#pragma unroll
  for (int p = 0; p < 8; ++p) {
    int r = p * 8 + h;
    int colb = (cw * 4) ^ ((r >> 2) << 2);
    uint4 pk = *(const uint4*)&tile[r * 128 + colb];
    *(uint4*)(dp + (size_t)r * CC + cw * 8) = pk;
  }
  if (tid < 64) {
    float s = 0.f;
#pragma unroll
    for (int k = 0; k < 16; ++k) s += part[k][tid];
    inv[b * SS + s0 + tid] = 1.0f / fmaxf(sqrtf(s), 1e-12f);
  }
}

// ---------------------------------------------------------------------------
// Launch 1: transnorm(qb,kb) + extras (negidx+out-zero, best-zero x4).
// grid = 1024 + 5.
// ---------------------------------------------------------------------------
__global__ __launch_bounds__(256, 4) void transnorm_kernel(
    const float* __restrict__ qb, const float* __restrict__ kb,
    unsigned short* __restrict__ qt, unsigned short* __restrict__ kt,
    float* __restrict__ invqb, float* __restrict__ invkb,
    const int* __restrict__ labels, int* __restrict__ negidx,
    unsigned long long* __restrict__ best, float* __restrict__ out) {
  const int bid = blockIdx.x;
  const int tid = threadIdx.x;

  __shared__ unsigned int tile[64 * 128];
  __shared__ float part[16][65];

  if (bid >= 1024) {
    if (bid == 1024) {
      // --- negidx: threefry u[32][32] + per-b argmax over different-label ---
      float* u = (float*)&tile[0];  // reuse LDS (needs 4 KB)
      tf_gen(tid, u);
      tf_gen(tid + 256, u);
      if (tid == 0) *out = 0.f;
      __syncthreads();
      if (tid < BB) {
        int lb = labels[tid];
        float bestv = -1.0f;
        int bj = 0;
        for (int j = 0; j < BB; ++j) {
          float v = (labels[j] != lb) ? u[tid * BB + j] : -1.0f;
          if (v > bestv) { bestv = v; bj = j; }
        }
        negidx[tid] = bj;
      }
    } else {
      // --- zero best: 4 blocks x 8192 u64 ---
      unsigned long long* bp = best + (size_t)(bid - 1025) * 8192 + tid;
#pragma unroll
      for (int i = 0; i < 32; ++i) bp[(size_t)i * 256] = 0ull;
    }
    return;
  }

  const int which = bid >> 9;       // 0:qb 1:kb
  const int sub = bid & 511;
  tn_body(which ? kb : qb, which ? kt : qt, which ? invkb : invqb, sub >> 4,
          (sub & 15) * 64, tid, tile, part);
}

// ---------------------------------------------------------------------------
// sim staging / compute (r6 2-phase bodies, unchanged)
// ---------------------------------------------------------------------------
__device__ __forceinline__ void sim_stage(
    const unsigned short* __restrict__ aG, const unsigned short* __restrict__ bG,
    unsigned short* SA, unsigned short* SB, int ch, int w, int r8, int p) {
#pragma unroll
  for (int v = 0; v < 4; ++v) {
    int r = v * 32 + w * 8 + r8;
    int clog = p ^ (r & 7);
    ASYNC16(aG + (size_t)r * CC + ch * 64 + clog * 8, &SA[(v * 32 + w * 8) * 64]);
    ASYNC16(bG + (size_t)r * CC + ch * 64 + clog * 8, &SB[(v * 32 + w * 8) * 64]);
  }
}

__device__ __forceinline__ void sim_compute(
    const unsigned short* SA, const unsigned short* SB, f32x4 acc[4][4],
    int wi, int wj, int q4, int m16) {
#pragma unroll
  for (int kk = 0; kk < 2; ++kk) {
    short8v af[4], bf[4];
#pragma unroll
    for (int mt = 0; mt < 4; ++mt) {
      int i = wi + mt * 16 + m16;
      int cp = (kk * 4 + q4) ^ (i & 7);
      af[mt] = *(const short8v*)&SA[i * 64 + cp * 8];
      int j = wj + mt * 16 + m16;
      int cq = (kk * 4 + q4) ^ (j & 7);
      bf[mt] = *(const short8v*)&SB[j * 64 + cq * 8];
    }
#pragma unroll
    for (int mt = 0; mt < 4; ++mt)
#pragma unroll
      for (int nt = 0; nt < 4; ++nt)
        acc[mt][nt] = __builtin_amdgcn_mfma_f32_16x16x32_bf16(
            af[mt], bf[nt], acc[mt][nt], 0, 0, 0);
  }
}

// ---------------------------------------------------------------------------
// Launch 2 (megasim): simargmax (2048 tiles) INTERLEAVED 4:1 with
// transnorm(kg) (512 strips, every 5th bid). Rationale (r5/r6 counters): sim
// is latency-bound (MfmaUtil 13%, HBM 0.4TB/s — mostly bubbles); tn-kg is
// BW-bound and independent — complementary resources, co-scheduled.
// LDS union in one 68KB carve -> 2 blocks/CU for both paths (tn proved
// occupancy-insensitive r1/r2). XCD-exact swizzle over the interleaved sim
// set: 40 = lcm(5,8) window, 4 sim blocks per XCD per window, bijective.
// grid = 2560.
// ---------------------------------------------------------------------------
__global__ __launch_bounds__(256, 2) void megasim_kernel(
    const unsigned short* __restrict__ qt, const unsigned short* __restrict__ kt,
    const float* __restrict__ invk, unsigned long long* __restrict__ best,
    const float* __restrict__ kg, unsigned short* __restrict__ kgt,
    float* __restrict__ invkg) {
  __shared__ __align__(16) char smem[68096];
  const int bid = blockIdx.x;
  const int t = threadIdx.x;

  if ((bid % 5) == 4) {
    // ---- transnorm(kg) strip ----
    const int tn_idx = bid / 5;  // 0..511
    tn_body(kg, kgt, invkg, tn_idx >> 4, (tn_idx & 15) * 64, t,
            (unsigned int*)smem, (float(*)[65])(smem + 32768));
    return;
  }

  // ---- sim path: exact XCD-contiguous rank within interleaved bid set ----
  const int x = bid & 7;                  // XCD (hw round-robin of bid)
  const int k = ((bid % 40) - x) >> 3;    // slot 0..4 within 40-bid window
  int o = 0;
#pragma unroll
  for (int kk = 0; kk < 4; ++kk)
    if (kk < k && ((x + 8 * kk) % 5) != 4) ++o;  // rank among sim slots
  const int W = x * 256 + (bid / 40) * 4 + o;    // 0..2047, bijective
  const int b = W >> 6, it = (W >> 3) & 7, jt = W & 7;
  const int w = t >> 6, l = t & 63;

  unsigned short* sa0 = (unsigned short*)(smem);
  unsigned short* sa1 = (unsigned short*)(smem + 16384);
  unsigned short* sb0 = (unsigned short*)(smem + 32768);
  unsigned short* sb1 = (unsigned short*)(smem + 49152);
  unsigned long long (*cand2)[2] = (unsigned long long(*)[2])(smem + 65536);
  float* sinvk = (float*)(smem + 65536 + 2048);

  if (t < 128) sinvk[t] = invk[b * SS + jt * 128 + t];

  const unsigned short* aG = qt + ((size_t)b * SS + it * 128) * CC;
  const unsigned short* bG = kt + ((size_t)b * SS + jt * 128) * CC;

  f32x4 acc[4][4];
#pragma unroll
  for (int mt = 0; mt < 4; ++mt)
#pragma unroll
    for (int nt = 0; nt < 4; ++nt) acc[mt][nt] = (f32x4){0.f, 0.f, 0.f, 0.f};

  const int r8 = l >> 3, p = l & 7;
  const int q4 = l >> 4, m16 = l & 15;
  const int wi = (w >> 1) * 64, wj = (w & 1) * 64;

  // ---- 2-phase pipeline over 4 K-chunks (r6) ----
  sim_stage(aG, bG, sa0, sb0, 0, w, r8, p);
  __syncthreads();
  sim_stage(aG, bG, sa1, sb1, 1, w, r8, p);
  sim_compute(sa0, sb0, acc, wi, wj, q4, m16);
  __syncthreads();
  sim_stage(aG, bG, sa0, sb0, 2, w, r8, p);
  sim_compute(sa1, sb1, acc, wi, wj, q4, m16);
  __syncthreads();
  sim_stage(aG, bG, sa1, sb1, 3, w, r8, p);
  sim_compute(sa0, sb0, acc, wi, wj, q4, m16);
  __syncthreads();
  sim_compute(sa1, sb1, acc, wi, wj, q4, m16);

  // ---- in-register argmax ----
  float siv[4];
#pragma unroll
  for (int nt = 0; nt < 4; ++nt) siv[nt] = sinvk[wj + nt * 16 + m16];

  unsigned long long bp[4][4];
#pragma unroll
  for (int mt = 0; mt < 4; ++mt) {
#pragma unroll
    for (int e = 0; e < 4; ++e) {
      unsigned long long mx = 0ull;
#pragma unroll
      for (int nt = 0; nt < 4; ++nt) {
        float v = acc[mt][nt][e] * siv[nt];
        unsigned int u = __float_as_uint(v);
        u = (u & 0x80000000u) ? ~u : (u | 0x80000000u);
        int col = jt * 128 + wj + nt * 16 + m16;
        unsigned long long pk =
            ((unsigned long long)u << 32) | (unsigned)(1023 - col);
        mx = (pk > mx) ? pk : mx;
      }
      bp[mt][e] = mx;
    }
  }
#pragma unroll
  for (int d = 1; d < 16; d <<= 1) {
#pragma unroll
    for (int mt = 0; mt < 4; ++mt)
#pragma unroll
      for (int e = 0; e < 4; ++e) {
        unsigned long long o2 = __shfl_xor(bp[mt][e], d, 64);
        if (o2 > bp[mt][e]) bp[mt][e] = o2;
      }
  }
  if (m16 == 0) {
#pragma unroll
    for (int mt = 0; mt < 4; ++mt)
#pragma unroll
      for (int e = 0; e < 4; ++e)
        cand2[wi + mt * 16 + q4 * 4 + e][w & 1] = bp[mt][e];
  }
  __syncthreads();
  if (t < 128) {
    unsigned long long m0 = cand2[t][0], m1 = cand2[t][1];
    atomicMax(&best[b * SS + it * 128 + t], m0 > m1 ? m0 : m1);
  }
}

// ---------------------------------------------------------------------------
// negidx standalone (fallback path only)
// ---------------------------------------------------------------------------
__global__ void negidx_kernel(const int* __restrict__ labels, int* __restrict__ negidx) {
  __shared__ float u[1024];
  int t = threadIdx.x;
  tf_gen(t, u);
  __syncthreads();
  if (t < BB) {
    int lb = labels[t];
    float bestv = -1.0f;
    int bj = 0;
    for (int j = 0; j < BB; ++j) {
      float v = (labels[j] != lb) ? u[t * BB + j] : -1.0f;
      if (v > bestv) { bestv = v; bj = j; }
    }
    negidx[t] = bj;
  }
}

// ---------------------------------------------------------------------------
// loss v2 (round-1 measured-best shape): 8 threads per (b,s); 1024 blocks.
// ---------------------------------------------------------------------------
__global__ __launch_bounds__(256) void loss_fused_kernel(
    const float* __restrict__ qg, const unsigned short* __restrict__ kgt,
    const float* __restrict__ invkg, const unsigned long long* __restrict__ best,
    const int* __restrict__ negidx, float* __restrict__ out) {
  const int tid = threadIdx.x;
  const int s_l = tid & 31, g = tid >> 5;
  const int P0 = blockIdx.x * 32;
  const int b = P0 >> 10;
  const int s = (P0 & (SS - 1)) + s_l;
  const int idx = b * SS + s;
  const int js = 1023 - (int)(best[idx] & 0xffffffffu);
  const int nb = negidx[b];

  const float* qcol = qg + ((size_t)b * CC + g * 32) * SS + s;
  const unsigned short* kp = kgt + ((size_t)b * SS + js) * CC + g * 32;
  const unsigned short* kn = kgt + ((size_t)nb * SS + s) * CC + g * 32;

  float dp = 0.f, dn = 0.f, sq = 0.f;
#pragma unroll
  for (int uu = 0; uu < 4; ++uu) {
    uint4 up = *(const uint4*)(kp + uu * 8);
    uint4 un = *(const uint4*)(kn + uu * 8);
    float q[8];
#pragma unroll
    for (int j = 0; j < 8; ++j) {
      q[j] = qcol[(size_t)(uu * 8 + j) << 10];
      sq = fmaf(q[j], q[j], sq);
    }
    float pv[8], nv[8];
    pv[0] = __uint_as_float(up.x << 16); pv[1] = __uint_as_float(up.x & 0xffff0000u);
    pv[2] = __uint_as_float(up.y << 16); pv[3] = __uint_as_float(up.y & 0xffff0000u);
    pv[4] = __uint_as_float(up.z << 16); pv[5] = __uint_as_float(up.z & 0xffff0000u);
    pv[6] = __uint_as_float(up.w << 16); pv[7] = __uint_as_float(up.w & 0xffff0000u);
    nv[0] = __uint_as_float(un.x << 16); nv[1] = __uint_as_float(un.x & 0xffff0000u);
    nv[2] = __uint_as_float(un.y << 16); nv[3] = __uint_as_float(un.y & 0xffff0000u);
    nv[4] = __uint_as_float(un.z << 16); nv[5] = __uint_as_float(un.z & 0xffff0000u);
    nv[6] = __uint_as_float(un.w << 16); nv[7] = __uint_as_float(un.w & 0xffff0000u);
#pragma unroll
    for (int j = 0; j < 8; ++j) {
      dp = fmaf(q[j], pv[j], dp);
      dn = fmaf(q[j], nv[j], dn);
    }
  }

  __shared__ float rdp[8][33], rdn[8][33], rsq[8][33];
  rdp[g][s_l] = dp;
  rdn[g][s_l] = dn;
  rsq[g][s_l] = sq;
  __syncthreads();
  if (tid < 32) {
    float DP = 0.f, DN = 0.f, SQ = 0.f;
#pragma unroll
    for (int k = 0; k < 8; ++k) {
      DP += rdp[k][tid];
      DN += rdn[k][tid];
      SQ += rsq[k][tid];
    }
    int s2 = (P0 & (SS - 1)) + tid;
    int idx2 = b * SS + s2;
    int js2 = 1023 - (int)(best[idx2] & 0xffffffffu);
    float iq = 1.0f / fmaxf(sqrtf(SQ), 1e-12f);
    float pvv = DP * iq * invkg[b * SS + js2] * 10.0f;
    float nvv = DN * iq * invkg[nb * SS + s2] * 10.0f;
    float elem = logf(expf(pvv) + expf(nvv) + 1e-6f) - pvv;
#pragma unroll
    for (int o = 16; o > 0; o >>= 1) elem += __shfl_down(elem, o, 32);
    if (tid == 0) atomicAdd(out, elem * (1.0f / (BB * SS)));
  }
}

// ===========================================================================
// Fallback path (ws too small): round-1 fp32 VALU, known correct.
// ===========================================================================
__global__ __launch_bounds__(256) void norms_kernel(
    const float* __restrict__ qb, const float* __restrict__ kb,
    const float* __restrict__ qg, const float* __restrict__ kg,
    float* __restrict__ inv) {
  int t = blockIdx.x * 256 + threadIdx.x;
  int which = t >> 15;
  int bs = t & (BB * SS - 1);
  const float* src = (which == 0) ? qb : (which == 1) ? kb : (which == 2) ? qg : kg;
  int b = bs >> 10;
  int s = bs & (SS - 1);
  const float* p = src + (size_t)b * CC * SS + s;
  float ss = 0.f;
#pragma unroll 8
  for (int c = 0; c < CC; ++c) {
    float x = p[(size_t)c * SS];
    ss = fmaf(x, x, ss);
  }
  float n = fmaxf(sqrtf(ss), 1e-12f);
  inv[t] = 1.0f / n;
}

#define TI 64
#define TJ 128
#define KC 32

__global__ __launch_bounds__(256) void simargmax_kernel(
    const float* __restrict__ qb, const float* __restrict__ kb,
    const float* __restrict__ invq, const float* __restrict__ invk,
    int* __restrict__ amax) {
  const int b = blockIdx.x >> 4;
  const int i0 = (blockIdx.x & 15) * TI;
  const int t = threadIdx.x;
  const int ti = t >> 4;
  const int tj = t & 15;

  __shared__ float aQ[KC][TI];
  __shared__ float bK[KC][TJ];
  __shared__ float redv[TI][16];
  __shared__ int redj[TI][16];

  const float* qbase = qb + (size_t)b * CC * SS + i0;
  const float* kbase = kb + (size_t)b * CC * SS;
  const float* ivq = invq + b * SS + i0;
  const float* ivk = invk + b * SS;

  float best_v = -3.4e38f;
  int best_j = 0;

  for (int j0 = 0; j0 < SS; j0 += TJ) {
    float acc[4][8];
#pragma unroll
    for (int r = 0; r < 4; ++r)
#pragma unroll
      for (int rr = 0; rr < 8; ++rr) acc[r][rr] = 0.f;

    for (int c0 = 0; c0 < CC; c0 += KC) {
      __syncthreads();
#pragma unroll
      for (int v = 0; v < 2; ++v) {
        int f = t + v * 256;
        int cl = f >> 4;
        int sl = (f & 15) << 2;
        float4 qa = *(const float4*)(qbase + (size_t)(c0 + cl) * SS + sl);
        float4 iv = *(const float4*)(ivq + sl);
        aQ[cl][sl + 0] = qa.x * iv.x;
        aQ[cl][sl + 1] = qa.y * iv.y;
        aQ[cl][sl + 2] = qa.z * iv.z;
        aQ[cl][sl + 3] = qa.w * iv.w;
      }
#pragma unroll
      for (int v = 0; v < 4; ++v) {
        int f = t + v * 256;
        int cl = f >> 5;
        int sl = (f & 31) << 2;
        float4 ka = *(const float4*)(kbase + (size_t)(c0 + cl) * SS + j0 + sl);
        float4 ik = *(const float4*)(ivk + j0 + sl);
        bK[cl][sl + 0] = ka.x * ik.x;
        bK[cl][sl + 1] = ka.y * ik.y;
        bK[cl][sl + 2] = ka.z * ik.z;
        bK[cl][sl + 3] = ka.w * ik.w;
      }
      __syncthreads();
#pragma unroll
      for (int kc = 0; kc < KC; ++kc) {
        float4 a0 = *(const float4*)&aQ[kc][ti * 4];
        float4 b0 = *(const float4*)&bK[kc][tj * 8];
        float4 b1 = *(const float4*)&bK[kc][tj * 8 + 4];
        float av[4] = {a0.x, a0.y, a0.z, a0.w};
        float bv[8] = {b0.x, b0.y, b0.z, b0.w, b1.x, b1.y, b1.z, b1.w};
#pragma unroll
        for (int r = 0; r < 4; ++r)
#pragma unroll
          for (int rr = 0; rr < 8; ++rr)
            acc[r][rr] = fmaf(av[r], bv[rr], acc[r][rr]);
      }
    }
    __syncthreads();
#pragma unroll
    for (int r = 0; r < 4; ++r) {
      float v = acc[r][0];
      int jb = j0 + tj * 8;
#pragma unroll
      for (int rr = 1; rr < 8; ++rr) {
        if (acc[r][rr] > v) { v = acc[r][rr]; jb = j0 + tj * 8 + rr; }
      }
      redv[ti * 4 + r][tj] = v;
      redj[ti * 4 + r][tj] = jb;
    }
    __syncthreads();
    if (t < TI) {
#pragma unroll
      for (int ww = 0; ww < 16; ++ww) {
        float v = redv[t][ww];
        if (v > best_v) { best_v = v; best_j = redj[t][ww]; }
      }
    }
  }
  if (t < TI) amax[b * SS + i0 + t] = best_j;
}

__global__ __launch_bounds__(256) void loss_kernel(
    const float* __restrict__ qg, const float* __restrict__ kg,
    const float* __restrict__ invq, const float* __restrict__ invk,
    const int* __restrict__ amax, const int* __restrict__ negidx,
    float* __restrict__ out) {
  int t = blockIdx.x * 256 + threadIdx.x;
  int b = t >> 10;
  int s = t & (SS - 1);
  int js = amax[t];
  int nb = negidx[b];
  const float* qcol = qg + (size_t)b * CC * SS + s;
  const float* kpcol = kg + (size_t)b * CC * SS + js;
  const float* kncol = kg + (size_t)nb * CC * SS + s;
  float dp = 0.f, dn = 0.f;
#pragma unroll 8
  for (int c = 0; c < CC; ++c) {
    float q = qcol[(size_t)c * SS];
    dp = fmaf(q, kpcol[(size_t)c * SS], dp);
    dn = fmaf(q, kncol[(size_t)c * SS], dn);
  }
  float iq = invq[t];
  float pv = dp * iq * invk[b * SS + js] * 10.0f;
  float nv = dn * iq * invk[nb * SS + s] * 10.0f;
  float elem = logf(expf(pv) + expf(nv) + 1e-6f) - pv;

  __shared__ float red[256];
  red[threadIdx.x] = elem;
  __syncthreads();
  for (int o = 128; o > 0; o >>= 1) {
    if (threadIdx.x < o) red[threadIdx.x] += red[threadIdx.x + o];
    __syncthreads();
  }
  if (threadIdx.x == 0) atomicAdd(out, red[0] * (1.0f / (BB * SS)));
}

// ---------------------------------------------------------------------------
extern "C" void kernel_launch(void* const* d_in, const int* in_sizes, int n_in,
                              void* d_out, int out_size, void* d_ws, size_t ws_size,
                              hipStream_t stream) {
  const float* qb = (const float*)d_in[0];
  const float* kb = (const float*)d_in[1];
  const float* qg = (const float*)d_in[2];
  const float* kg = (const float*)d_in[3];
  const int* labels = (const int*)d_in[4];

  char* ws = (char*)d_ws;
  // fast-path layout (49 MB total):
  float* invqb = (float*)ws;                                   // 128 KB (unused)
  float* invkb = (float*)(ws + 128 * 1024);                    // 128 KB
  float* invkg = (float*)(ws + 256 * 1024);                    // 128 KB
  unsigned long long* best = (unsigned long long*)(ws + 384 * 1024);  // 256 KB
  int* negidx = (int*)(ws + 640 * 1024);                       // small
  unsigned short* qt = (unsigned short*)(ws + (1 << 20));      // 16 MB
  unsigned short* kt = (unsigned short*)(ws + (17 << 20));     // 16 MB
  unsigned short* kgt = (unsigned short*)(ws + (33 << 20));    // 16 MB

  const size_t need = (size_t)49 * 1024 * 1024;
  const bool fast = ws_size >= need;

  if (fast) {
    transnorm_kernel<<<1029, 256, 0, stream>>>(qb, kb, qt, kt, invqb, invkb,
                                               labels, negidx, best,
                                               (float*)d_out);
    megasim_kernel<<<2560, 256, 0, stream>>>(qt, kt, invkb, best, kg, kgt,
                                             invkg);
    loss_fused_kernel<<<1024, 256, 0, stream>>>(qg, kgt, invkg, best, negidx,
                                                (float*)d_out);
  } else {
    hipMemsetAsync(d_out, 0, sizeof(float), stream);
    float* inv = (float*)ws;
    int* amax = (int*)(ws + 512 * 1024);
    int* negidx2 = (int*)(ws + 640 * 1024);
    norms_kernel<<<(4 * BB * SS) / 256, 256, 0, stream>>>(qb, kb, qg, kg, inv);
    simargmax_kernel<<<BB * (SS / TI), 256, 0, stream>>>(
        qb, kb, inv + 0 * BB * SS, inv + 1 * BB * SS, amax);
    negidx_kernel<<<1, 512, 0, stream>>>(labels, negidx2);
    loss_kernel<<<(BB * SS) / 256, 256, 0, stream>>>(
        qg, kg, inv + 2 * BB * SS, inv + 3 * BB * SS, amax, negidx2,
        (float*)d_out);
  }
}